// Round 5
// baseline (111.754 us; speedup 1.0000x reference)
//
#include <hip/hip_runtime.h>
#include <hip/hip_bf16.h>

// out[b,w] = relu(sqrt(max(||x_b||^2 + ||w_w||^2 - 2*x_b.w_w, 0)) / sqrt(512))
// M=8192, N=4096, K=512. bf16 MFMA NT-GEMM.
// R1 core (128x128 tile, BK=64, 4 waves, single-buffer LDS, 2 barriers/step,
// global_load_lds width 16) + persistent tile-chaining: each block does 4
// consecutive N-tiles with one A panel; next tile's first stage is issued
// before the epilogue so prologue latency hides under epilogue VALU/stores.

typedef __bf16 bf16x8 __attribute__((ext_vector_type(8)));
typedef float f32x4 __attribute__((ext_vector_type(4)));

#define K_DIM 512
#define NT 8      // K-steps per tile (K/64)
#define CHAIN 4   // tiles per block along N
#define INV_SCALE 0.04419417382415922f  // 1/22.627417

__device__ __forceinline__ ushort f2bf(float f) {
  __hip_bfloat16 h = __float2bfloat16(f);
  return __builtin_bit_cast(ushort, h);
}

// fp32 -> bf16 convert + row sum of squares. One 128-thread block per row.
__global__ __launch_bounds__(128) void convert_kernel(
    const float* __restrict__ x, const float* __restrict__ w,
    ushort* __restrict__ xb, ushort* __restrict__ wb,
    float* __restrict__ xsq, float* __restrict__ wsq, int M) {
  int b = blockIdx.x;
  const float* src; ushort* dst; float* sq; int row;
  if (b < M) { src = x; dst = xb; sq = xsq; row = b; }
  else       { src = w; dst = wb; sq = wsq; row = b - M; }
  int t = threadIdx.x;
  float4 v = reinterpret_cast<const float4*>(src + (size_t)row * K_DIM)[t];
  ushort4 p;
  p.x = f2bf(v.x); p.y = f2bf(v.y); p.z = f2bf(v.z); p.w = f2bf(v.w);
  reinterpret_cast<ushort4*>(dst + (size_t)row * K_DIM)[t] = p;
  float s = v.x * v.x + v.y * v.y + v.z * v.z + v.w * v.w;
#pragma unroll
  for (int o = 32; o > 0; o >>= 1) s += __shfl_down(s, o, 64);
  __shared__ float red[2];
  if ((t & 63) == 0) red[t >> 6] = s;
  __syncthreads();
  if (t == 0) sq[row] = red[0] + red[1];
}

__global__ __launch_bounds__(256) void gemm_dist_kernel(
    const ushort* __restrict__ xb, const ushort* __restrict__ wb,
    const float* __restrict__ xsq, const float* __restrict__ wsq,
    float* __restrict__ out, int M, int N) {
  __shared__ ushort Asm[128 * 64];  // 16 KB
  __shared__ ushort Bsm[128 * 64];  // 16 KB

  const int ntCh = N >> 9;                // 8 chain-groups along N
  const int nwg = gridDim.x;              // 512, % 8 == 0
  const int bid = blockIdx.x;
  const int swz = (bid & 7) * (nwg >> 3) + (bid >> 3);  // XCD-aware, bijective
  const int tR = swz / ntCh, tG = swz - tR * ntCh;
  const int rowA0 = tR << 7;
  const int colB0 = tG << 9;              // 4-tile chain base

  const int tid = threadIdx.x;
  const int wid = tid >> 6, lane = tid & 63;
  const int wr = wid >> 1, wc = wid & 1;  // 2x2 wave grid, wave out = 64x64
  const int l15 = lane & 15, l4 = lane >> 4;

  // Staging map (R1): wave wid covers tile rows [wid*32, wid*32+32) in 4 gll
  // of 8 rows each; lane -> row +(lane>>3), col chunk (lane&7)*8 (16B/lane).
  const int srow = (wid << 5) + (lane >> 3);
  const int scol = (lane & 7) << 3;
  const ushort* gA  = xb + (size_t)(rowA0 + srow) * K_DIM + scol;
  const ushort* gB0 = wb + (size_t)(colB0 + srow) * K_DIM + scol;

  f32x4 acc[4][4] = {};

#define STAGE(gBp, kt) do {                                                    \
    _Pragma("unroll")                                                          \
    for (int c8 = 0; c8 < 4; ++c8) {                                           \
      const int r0 = (wid << 5) + (c8 << 3);                                   \
      __builtin_amdgcn_global_load_lds(                                        \
          (const __attribute__((address_space(1))) void*)                      \
              (gA + (size_t)(c8 * 8) * K_DIM + (kt)),                          \
          (__attribute__((address_space(3))) void*)&Asm[r0 * 64], 16, 0, 0);   \
      __builtin_amdgcn_global_load_lds(                                        \
          (const __attribute__((address_space(1))) void*)                      \
              ((gBp) + (size_t)(c8 * 8) * K_DIM + (kt)),                       \
          (__attribute__((address_space(3))) void*)&Bsm[r0 * 64], 16, 0, 0);   \
    } } while (0)

  // First prologue (only un-hidden one per block).
  STAGE(gB0, 0);

  // Hoisted row norms (c-independent, statically indexed).
  const int rBase = rowA0 + (wr << 6) + (l4 << 2);
  float xq[4][4];
#pragma unroll
  for (int i = 0; i < 4; ++i)
#pragma unroll
    for (int r = 0; r < 4; ++r) xq[i][r] = xsq[rBase + (i << 4) + r];

  for (int c = 0; c < CHAIN; ++c) {
    const ushort* gBc = gB0 + (size_t)c * 128 * K_DIM;
#pragma unroll
    for (int t = 0; t < NT; ++t) {
      __syncthreads();  // publish staged tile (compiler drains vmcnt here)
#pragma unroll
      for (int kk = 0; kk < 2; ++kk) {
        bf16x8 af[4], bg[4];
        const int ko = (kk << 5) + (l4 << 3);
#pragma unroll
        for (int i = 0; i < 4; ++i)
          af[i] = *reinterpret_cast<const bf16x8*>(
              &Asm[((wr << 6) + (i << 4) + l15) * 64 + ko]);
#pragma unroll
        for (int j = 0; j < 4; ++j)
          bg[j] = *reinterpret_cast<const bf16x8*>(
              &Bsm[((wc << 6) + (j << 4) + l15) * 64 + ko]);
#pragma unroll
        for (int i = 0; i < 4; ++i)
#pragma unroll
          for (int j = 0; j < 4; ++j)
            acc[i][j] = __builtin_amdgcn_mfma_f32_16x16x32_bf16(
                af[i], bg[j], acc[i][j], 0, 0, 0);
      }
      __syncthreads();  // LDS consumed, safe to overwrite
      if (t + 1 < NT)           STAGE(gBc, (t + 1) * 64);
      else if (c + 1 < CHAIN)   STAGE(gBc + (size_t)128 * K_DIM, 0);
      // (last tile, last step: nothing left to stage)
    }

    // Epilogue for tile c — runs while the just-issued next-tile stage lands.
    // C/D mapping: col = lane&15, row = (lane>>4)*4 + reg.
    const int cBase = colB0 + (c << 7) + (wc << 6) + l15;
    float wq0 = wsq[cBase];
    float wq1 = wsq[cBase + 16];
    float wq2 = wsq[cBase + 32];
    float wq3 = wsq[cBase + 48];
#pragma unroll
    for (int i = 0; i < 4; ++i)
#pragma unroll
      for (int r = 0; r < 4; ++r) {
        const int row = rBase + (i << 4) + r;
        const float xqv = xq[i][r];
        const size_t ro = (size_t)row * (size_t)N;
        float v0 = xqv + wq0 - 2.0f * acc[i][0][r];
        float v1 = xqv + wq1 - 2.0f * acc[i][1][r];
        float v2 = xqv + wq2 - 2.0f * acc[i][2][r];
        float v3 = xqv + wq3 - 2.0f * acc[i][3][r];
        out[ro + cBase]      = sqrtf(fmaxf(v0, 0.0f)) * INV_SCALE;
        out[ro + cBase + 16] = sqrtf(fmaxf(v1, 0.0f)) * INV_SCALE;
        out[ro + cBase + 32] = sqrtf(fmaxf(v2, 0.0f)) * INV_SCALE;
        out[ro + cBase + 48] = sqrtf(fmaxf(v3, 0.0f)) * INV_SCALE;
      }
#pragma unroll
    for (int i = 0; i < 4; ++i)
#pragma unroll
      for (int j = 0; j < 4; ++j) acc[i][j] = (f32x4){0.f, 0.f, 0.f, 0.f};
  }
#undef STAGE
}

extern "C" void kernel_launch(void* const* d_in, const int* in_sizes, int n_in,
                              void* d_out, int out_size, void* d_ws, size_t ws_size,
                              hipStream_t stream) {
  const float* x = (const float*)d_in[0];   // (M, 512) fp32
  const float* w = (const float*)d_in[1];   // (N, 512) fp32
  const int M = in_sizes[0] / K_DIM;        // 8192
  const int N = in_sizes[1] / K_DIM;        // 4096
  float* out = (float*)d_out;

  char* ws = (char*)d_ws;
  ushort* xb = (ushort*)ws;
  ushort* wb = (ushort*)(ws + (size_t)M * K_DIM * 2);
  float* xsq = (float*)(ws + (size_t)M * K_DIM * 2 + (size_t)N * K_DIM * 2);
  float* wsq = xsq + M;

  convert_kernel<<<M + N, 128, 0, stream>>>(x, w, xb, wb, xsq, wsq, M);

  dim3 grid((M >> 7) * (N >> 9));  // 64 * 8 = 512 blocks, 4 tiles each
  gemm_dist_kernel<<<grid, 256, 0, stream>>>(xb, wb, xsq, wsq, out, M, N);
}

// Round 6
// 60.994 us; speedup vs baseline: 1.8322x; 1.8322x over previous
//
#include <hip/hip_runtime.h>
#include <hip/hip_bf16.h>

// out[b,w] = relu(sqrt(max(||x_b||^2 + ||w_w||^2 - 2*x_b.w_w, 0)) / sqrt(512))
// M=8192, N=4096, K=512. bf16 MFMA NT-GEMM.
// R1 structure exactly (128x128 tile, BK=64, 4 waves, single-buffer LDS,
// 2 barriers/K-step, global_load_lds width 16, 2048 blocks) + ONE change:
// T2 XOR-swizzle on A and B LDS tiles (pre-swizzled global source chunk +
// swizzled ds_read), eliminating the measured 16-way bank conflict
// (SQ_LDS_BANK_CONFLICT = 1.26e7 in the R4 profile, same read pattern).

typedef __bf16 bf16x8 __attribute__((ext_vector_type(8)));
typedef float f32x4 __attribute__((ext_vector_type(4)));

#define K_DIM 512
#define INV_SCALE 0.04419417382415922f  // 1/22.627417

__device__ __forceinline__ ushort f2bf(float f) {
  __hip_bfloat16 h = __float2bfloat16(f);
  return __builtin_bit_cast(ushort, h);
}

// fp32 -> bf16 convert + row sum of squares. One 128-thread block per row.
__global__ __launch_bounds__(128) void convert_kernel(
    const float* __restrict__ x, const float* __restrict__ w,
    ushort* __restrict__ xb, ushort* __restrict__ wb,
    float* __restrict__ xsq, float* __restrict__ wsq, int M) {
  int b = blockIdx.x;
  const float* src; ushort* dst; float* sq; int row;
  if (b < M) { src = x; dst = xb; sq = xsq; row = b; }
  else       { src = w; dst = wb; sq = wsq; row = b - M; }
  int t = threadIdx.x;
  float4 v = reinterpret_cast<const float4*>(src + (size_t)row * K_DIM)[t];
  ushort4 p;
  p.x = f2bf(v.x); p.y = f2bf(v.y); p.z = f2bf(v.z); p.w = f2bf(v.w);
  reinterpret_cast<ushort4*>(dst + (size_t)row * K_DIM)[t] = p;
  float s = v.x * v.x + v.y * v.y + v.z * v.z + v.w * v.w;
#pragma unroll
  for (int o = 32; o > 0; o >>= 1) s += __shfl_down(s, o, 64);
  __shared__ float red[2];
  if ((t & 63) == 0) red[t >> 6] = s;
  __syncthreads();
  if (t == 0) sq[row] = red[0] + red[1];
}

// LDS holds (row, ch) = global(row, ch ^ (row&7)) for both A and B.
// Staging: linear gll dest; per-lane source chunk = (lane&7) ^ (lane>>3),
// and row&7 == lane>>3 in this map, so LDS ends up swizzled correctly.
// Reads XOR the chunk with (row&7): lanes 0-15 then hit 8 distinct bank
// quads (2-way residual = free, m136) instead of 16-way on one quad.
__global__ void gemm_dist_kernel(
    const ushort* __restrict__ xb, const ushort* __restrict__ wb,
    const float* __restrict__ xsq, const float* __restrict__ wsq,
    float* __restrict__ out, int M, int N) {
  __shared__ ushort Asm[128 * 64];  // 16 KB
  __shared__ ushort Bsm[128 * 64];  // 16 KB

  const int ntN = N >> 7;
  const int nwg = gridDim.x;
  const int bid = blockIdx.x;
  const int swz = ((nwg & 7) == 0) ? ((bid & 7) * (nwg >> 3) + (bid >> 3)) : bid;
  const int tR = swz / ntN;
  const int tC = swz - tR * ntN;

  const int tid = threadIdx.x;
  const int wid = tid >> 6;
  const int lane = tid & 63;
  const int wr = wid >> 1, wc = wid & 1;
  const int l15 = lane & 15, l4 = lane >> 4;

  const int rowA0 = tR << 7;
  const int rowB0 = tC << 7;

  f32x4 acc[4][4] = {};

  // Staging map: wave wid covers tile rows [wid*32, wid*32+32) in 4 calls of
  // 8 rows each; lane l -> row +(l>>3). Source chunk pre-swizzled: (l&7)^(l>>3)
  // (row&7 == l>>3 here), so linear LDS dest yields the swizzled layout.
  const int srow = (wid << 5) + (lane >> 3);
  const int scol = ((lane & 7) ^ (lane >> 3)) << 3;
  const ushort* gA = xb + (size_t)(rowA0 + srow) * K_DIM + scol;
  const ushort* gB = wb + (size_t)(rowB0 + srow) * K_DIM + scol;

  for (int kt = 0; kt < K_DIM; kt += 64) {
#pragma unroll
    for (int c = 0; c < 4; ++c) {
      const int r0 = (wid << 5) + (c << 3);  // wave-uniform LDS row base
      __builtin_amdgcn_global_load_lds(
          (const __attribute__((address_space(1))) void*)(gA + (size_t)(c * 8) * K_DIM + kt),
          (__attribute__((address_space(3))) void*)&Asm[r0 * 64], 16, 0, 0);
      __builtin_amdgcn_global_load_lds(
          (const __attribute__((address_space(1))) void*)(gB + (size_t)(c * 8) * K_DIM + kt),
          (__attribute__((address_space(3))) void*)&Bsm[r0 * 64], 16, 0, 0);
    }
    __syncthreads();  // compiler emits vmcnt(0) drain before s_barrier

    const int axor = l15 & 7;  // row&7 for this lane's fragment rows
#pragma unroll
    for (int kk = 0; kk < 2; ++kk) {
      bf16x8 af[4], bfr[4];
      const int cx = (((kk << 2) + l4) ^ axor) << 3;  // swizzled chunk offset
#pragma unroll
      for (int i = 0; i < 4; ++i) {
        af[i]  = *reinterpret_cast<const bf16x8*>(
            &Asm[((wr << 6) + (i << 4) + l15) * 64 + cx]);
        bfr[i] = *reinterpret_cast<const bf16x8*>(
            &Bsm[((wc << 6) + (i << 4) + l15) * 64 + cx]);
      }
#pragma unroll
      for (int i = 0; i < 4; ++i)
#pragma unroll
        for (int j = 0; j < 4; ++j)
          acc[i][j] = __builtin_amdgcn_mfma_f32_16x16x32_bf16(af[i], bfr[j], acc[i][j], 0, 0, 0);
    }
    __syncthreads();
  }

  // Epilogue (R1 exact). C/D mapping: col = lane&15, row = (lane>>4)*4 + reg.
  const int colBase = rowB0 + (wc << 6) + l15;
  const int rowBase = rowA0 + (wr << 6) + (l4 << 2);
  float xq[4][4];
#pragma unroll
  for (int i = 0; i < 4; ++i)
#pragma unroll
    for (int r = 0; r < 4; ++r) xq[i][r] = xsq[rowBase + (i << 4) + r];
  float wq[4];
#pragma unroll
  for (int j = 0; j < 4; ++j) wq[j] = wsq[colBase + (j << 4)];

#pragma unroll
  for (int i = 0; i < 4; ++i) {
#pragma unroll
    for (int r = 0; r < 4; ++r) {
      const size_t rbase = (size_t)(rowBase + (i << 4) + r) * (size_t)N;
#pragma unroll
      for (int j = 0; j < 4; ++j) {
        float v = xq[i][r] + wq[j] - 2.0f * acc[i][j][r];
        v = fmaxf(v, 0.0f);
        out[rbase + colBase + (j << 4)] = sqrtf(v) * INV_SCALE;
      }
    }
  }
}

extern "C" void kernel_launch(void* const* d_in, const int* in_sizes, int n_in,
                              void* d_out, int out_size, void* d_ws, size_t ws_size,
                              hipStream_t stream) {
  const float* x = (const float*)d_in[0];   // (M, 512) fp32
  const float* w = (const float*)d_in[1];   // (N, 512) fp32
  const int M = in_sizes[0] / K_DIM;        // 8192
  const int N = in_sizes[1] / K_DIM;        // 4096
  float* out = (float*)d_out;

  char* ws = (char*)d_ws;
  ushort* xb = (ushort*)ws;
  ushort* wb = (ushort*)(ws + (size_t)M * K_DIM * 2);
  float* xsq = (float*)(ws + (size_t)M * K_DIM * 2 + (size_t)N * K_DIM * 2);
  float* wsq = xsq + M;

  convert_kernel<<<M + N, 128, 0, stream>>>(x, w, xb, wb, xsq, wsq, M);

  dim3 grid((M >> 7) * (N >> 7));  // 64 * 32 = 2048
  gemm_dist_kernel<<<grid, 256, 0, stream>>>(xb, wb, xsq, wsq, out, M, N);
}